// Round 7
// baseline (411.801 us; speedup 1.0000x reference)
//
#include <hip/hip_runtime.h>

// ---------------------------------------------------------------------------
// SortNet: 3-layer 1x1-conv MLP (64->64->16->1) with training-mode BatchNorm
// + ReLU, per-batch top-64 over N, gather of input + score.
//
// R7 GEMM shape: block = 512 thr = 8 waves; wave g = channel group (weights
// s_loaded, wave-uniform), lane = 2 consecutive positions (coalesced float2
// global loads of x; all 8 waves hit the same lines -> L1 broadcast).
// Per f: 1 load + 16 FMA, live ~45 VGPR (far from the R3/R4 remat cliff).
// k_stat0 has NO LDS and NO barriers; k_layer01 uses one 32KB h0 exchange
// (2 barriers per 128-pos tile) for conv1.
//
// Pipeline: memset, k_prep, k_stat0, k_reduce0, k_layer01, k_reduce1,
//   k_layer2(+hist), k_thresh, k_compact, k_final. All deterministic.
// ---------------------------------------------------------------------------

constexpr int   B_   = 16;
constexpr int   N_   = 32768;
constexpr int   K_   = 64;            // TOP_K
constexpr long long S_ = (long long)B_ * N_;   // 524288
constexpr float EPS_ = 1e-5f;

constexpr int T128  = 4096;   // 128-position tiles (S/128)
constexpr int NS0B  = 1024;   // k_stat0 blocks (4 tiles each)
constexpr int NL1B  = 1024;   // k_layer01 blocks (4 tiles each)
constexpr int NB2   = 256;    // k_layer2 blocks (2048 pos each)
constexpr int NBC   = 128;    // k_compact blocks (4096 pos each)
constexpr int NBINS = 4096;   // radix-select bins (key >> 20)
constexpr int CAP   = 1024;   // candidate capacity per batch

__device__ __forceinline__ unsigned key_map(float f) {
  unsigned u = __float_as_uint(f);
  return (u & 0x80000000u) ? ~u : (u | 0x80000000u);
}

// --------------------------- k_prep ----------------------------------------
__global__ __launch_bounds__(256) void k_prep(const float* __restrict__ w0,
                                              const float* __restrict__ w1,
                                              float* __restrict__ w0T,
                                              float* __restrict__ w1T) {
  int t = threadIdx.x;
  for (int e = t; e < 64 * 64; e += 256) {
    int o = e >> 6, f = e & 63;
    w0T[f * 64 + o] = w0[e];          // w0T[f][o] = w0[o][f]
  }
  for (int e = t; e < 16 * 64; e += 256) {
    int o = e >> 6, c = e & 63;
    w1T[c * 16 + o] = w1[e];          // w1T[c][o] = w1[o][c]
  }
}

// --------------------------- k_stat0 ---------------------------------------
// 8 waves/block; wave g -> channels g*8..g*8+7; lane -> positions 2l,2l+1.
// No LDS, no barriers. Per f: coalesced float2 load + 8 s_load weights +
// 16 FMA. Live: y[8]x2 + s1/s2[8] ~ 45 VGPR.
__global__ __launch_bounds__(512) void k_stat0(const float* __restrict__ sv,
                                               const float* __restrict__ w0T,
                                               const float* __restrict__ b0,
                                               float* __restrict__ p0) {
  const int t    = threadIdx.x;
  const int lane = t & 63;
  const int g    = __builtin_amdgcn_readfirstlane(t >> 6);   // wave id 0..7

  float bb[8];
#pragma unroll
  for (int j = 0; j < 8; ++j) bb[j] = b0[g * 8 + j];

  float s1[8], s2[8];
#pragma unroll
  for (int j = 0; j < 8; ++j) { s1[j] = 0.f; s2[j] = 0.f; }

  for (int tile = blockIdx.x; tile < T128; tile += NS0B) {
    const int b  = tile >> 8;                 // 256 tiles per batch
    const int n0 = (tile & 255) << 7;
    const float* xp = sv + ((long long)b * 64) * N_ + n0 + (lane << 1);

    float2 y[8];
#pragma unroll
    for (int j = 0; j < 8; ++j) { y[j].x = bb[j]; y[j].y = bb[j]; }
#pragma unroll
    for (int f = 0; f < 64; ++f) {
      const float2 x = *(const float2*)(xp + (long long)f * N_);
      const float* wr = w0T + f * 64 + g * 8;   // wave-uniform -> s_load
#pragma unroll
      for (int j = 0; j < 8; ++j) {
        y[j].x = fmaf(wr[j], x.x, y[j].x);
        y[j].y = fmaf(wr[j], x.y, y[j].y);
      }
    }
#pragma unroll
    for (int j = 0; j < 8; ++j) {
      s1[j] += y[j].x + y[j].y;
      s2[j] = fmaf(y[j].x, y[j].x, fmaf(y[j].y, y[j].y, s2[j]));
    }
  }

#pragma unroll
  for (int j = 0; j < 8; ++j) {
#pragma unroll
    for (int off = 32; off; off >>= 1) {
      s1[j] += __shfl_down(s1[j], off, 64);
      s2[j] += __shfl_down(s2[j], off, 64);
    }
  }
  if (lane == 0) {
    float* dst = p0 + (long long)blockIdx.x * 128;
#pragma unroll
    for (int j = 0; j < 8; ++j) {
      dst[g * 8 + j]      = s1[j];
      dst[64 + g * 8 + j] = s2[j];
    }
  }
}

// --------------------------- k_reduce0 -------------------------------------
// 1024 partials x 128; 8 groups x 128 slots, 4 streams each.
__global__ __launch_bounds__(1024) void k_reduce0(const float* __restrict__ p0,
                                                  const float* __restrict__ g,
                                                  const float* __restrict__ bt,
                                                  float* __restrict__ st) {
  __shared__ float l[8][128];
  const int t = threadIdx.x;
  const int j = t & 127, grp = t >> 7;
  float a0 = 0.f, a1 = 0.f, a2 = 0.f, a3 = 0.f;
  for (int i = grp; i < 256; i += 8) {
    a0 += p0[(long long)i * 128 + j];
    a1 += p0[(long long)(i + 256) * 128 + j];
    a2 += p0[(long long)(i + 512) * 128 + j];
    a3 += p0[(long long)(i + 768) * 128 + j];
  }
  l[grp][j] = (a0 + a1) + (a2 + a3);
  __syncthreads();
  if (t < 128) {
    float v = ((l[0][t] + l[1][t]) + (l[2][t] + l[3][t])) +
              ((l[4][t] + l[5][t]) + (l[6][t] + l[7][t]));
    l[0][t] = v;
  }
  __syncthreads();
  if (t < 64) {
    const float inv = 1.f / (float)S_;
    float mean = l[0][t] * inv;
    float ex2  = l[0][64 + t] * inv;
    float var  = ex2 - mean * mean;
    float sc   = g[t] * rsqrtf(var + EPS_);
    st[t]      = sc;
    st[64 + t] = bt[t] - mean * sc;
  }
}

// --------------------------- k_layer01 -------------------------------------
// Same conv0 shape as k_stat0; bn0+relu -> LDS h0[64][128] (32KB); conv1:
// wave g -> out-ch {2g, 2g+1}, 2 pos/lane. 2 barriers per 128-pos tile.
__global__ __launch_bounds__(512) void k_layer01(const float* __restrict__ sv,
                                                 const float* __restrict__ w0T,
                                                 const float* __restrict__ b0,
                                                 const float* __restrict__ st0,
                                                 const float* __restrict__ w1T,
                                                 const float* __restrict__ b1,
                                                 float* __restrict__ y1,
                                                 float* __restrict__ p1) {
  __shared__ float h0[64][128];
  const int t    = threadIdx.x;
  const int lane = t & 63;
  const int g    = __builtin_amdgcn_readfirstlane(t >> 6);

  float bb[8], sc[8], sh[8];
#pragma unroll
  for (int j = 0; j < 8; ++j) {
    bb[j] = b0[g * 8 + j];
    sc[j] = st0[g * 8 + j];
    sh[j] = st0[64 + g * 8 + j];
  }
  const float b10 = b1[2 * g], b11 = b1[2 * g + 1];

  float sA0 = 0.f, qA0 = 0.f, sA1 = 0.f, qA1 = 0.f;

  for (int tile = blockIdx.x; tile < T128; tile += NL1B) {
    const int b  = tile >> 8;
    const int n0 = (tile & 255) << 7;
    const float* xp = sv + ((long long)b * 64) * N_ + n0 + (lane << 1);

    // ---- conv0: 8 ch x 2 pos, x direct from global (L1-broadcast)
    float2 y[8];
#pragma unroll
    for (int j = 0; j < 8; ++j) { y[j].x = bb[j]; y[j].y = bb[j]; }
#pragma unroll
    for (int f = 0; f < 64; ++f) {
      const float2 x = *(const float2*)(xp + (long long)f * N_);
      const float* wr = w0T + f * 64 + g * 8;   // wave-uniform -> s_load
#pragma unroll
      for (int j = 0; j < 8; ++j) {
        y[j].x = fmaf(wr[j], x.x, y[j].x);
        y[j].y = fmaf(wr[j], x.y, y[j].y);
      }
    }

    __syncthreads();                  // prev tile's conv1 reads done
#pragma unroll
    for (int j = 0; j < 8; ++j) {
      float2 h;
      h.x = fmaf(y[j].x, sc[j], sh[j]); h.x = h.x > 0.f ? h.x : 0.f;
      h.y = fmaf(y[j].y, sc[j], sh[j]); h.y = h.y > 0.f ? h.y : 0.f;
      *(float2*)&h0[g * 8 + j][lane << 1] = h;
    }
    __syncthreads();                  // h0 complete

    // ---- conv1: out-ch {2g, 2g+1} x 2 pos
    float2 z0, z1;
    z0.x = b10; z0.y = b10; z1.x = b11; z1.y = b11;
#pragma unroll
    for (int c = 0; c < 64; ++c) {
      const float2 h = *(const float2*)&h0[c][lane << 1];
      const float* wr = w1T + c * 16 + 2 * g;   // wave-uniform -> s_load
      z0.x = fmaf(wr[0], h.x, z0.x); z0.y = fmaf(wr[0], h.y, z0.y);
      z1.x = fmaf(wr[1], h.x, z1.x); z1.y = fmaf(wr[1], h.y, z1.y);
    }

    float* yo = y1 + ((long long)(b * 16 + 2 * g)) * N_ + n0 + (lane << 1);
    *(float2*)yo        = z0;
    *(float2*)(yo + N_) = z1;

    sA0 += z0.x + z0.y;
    qA0 = fmaf(z0.x, z0.x, fmaf(z0.y, z0.y, qA0));
    sA1 += z1.x + z1.y;
    qA1 = fmaf(z1.x, z1.x, fmaf(z1.y, z1.y, qA1));
  }

#pragma unroll
  for (int off = 32; off; off >>= 1) {
    sA0 += __shfl_down(sA0, off, 64);
    qA0 += __shfl_down(qA0, off, 64);
    sA1 += __shfl_down(sA1, off, 64);
    qA1 += __shfl_down(qA1, off, 64);
  }
  if (lane == 0) {
    float* dst = p1 + (long long)blockIdx.x * 32;
    dst[2 * g]          = sA0;
    dst[2 * g + 1]      = sA1;
    dst[16 + 2 * g]     = qA0;
    dst[16 + 2 * g + 1] = qA1;
  }
}

// --------------------------- k_reduce1 -------------------------------------
// 1024 partials x 32; 32 groups x 32 slots, 2 streams each.
__global__ __launch_bounds__(1024) void k_reduce1(const float* __restrict__ p1,
                                                  const float* __restrict__ g,
                                                  const float* __restrict__ bt,
                                                  float* __restrict__ st) {
  __shared__ float l[32][32];
  const int t = threadIdx.x;
  const int j = t & 31, grp = t >> 5;
  float a0 = 0.f, a1 = 0.f;
  for (int i = grp; i < 512; i += 32) {
    a0 += p1[(long long)i * 32 + j];
    a1 += p1[(long long)(i + 512) * 32 + j];
  }
  l[grp][j] = a0 + a1;
  __syncthreads();
  if (t < 32) {
    float v = 0.f;
#pragma unroll
    for (int g2 = 0; g2 < 32; ++g2) v += l[g2][t];
    l[0][t] = v;
  }
  __syncthreads();
  if (t < 16) {
    const float inv = 1.f / (float)S_;
    float mean = l[0][t] * inv;
    float ex2  = l[0][16 + t] * inv;
    float var  = ex2 - mean * mean;
    float sc   = g[t] * rsqrtf(var + EPS_);
    st[t]      = sc;
    st[16 + t] = bt[t] - mean * sc;
  }
}

// --------------------------- k_layer2 --------------------------------------
__global__ __launch_bounds__(1024) void k_layer2(const float* __restrict__ y1,
                                                 const float* __restrict__ st1,
                                                 const float* __restrict__ w2,
                                                 const float* __restrict__ b2,
                                                 float* __restrict__ y2,
                                                 float* __restrict__ p2,
                                                 int* __restrict__ ghist) {
  __shared__ int hist[NBINS];
  __shared__ float ls[16], lq[16];
  const int t   = threadIdx.x;
  const int blk = blockIdx.x;
  const int b   = blk >> 4;
  const int n0  = ((blk & 15) << 11) | (t << 1);   // 2048 positions per block

#pragma unroll
  for (int i = 0; i < NBINS / 1024; ++i) hist[t + i * 1024] = 0;

  float sc[16], sh[16], w[16];
#pragma unroll
  for (int c = 0; c < 16; ++c) { sc[c] = st1[c]; sh[c] = st1[16 + c]; w[c] = w2[c]; }
  const float bias = b2[0];

  float a0 = bias, a1 = bias;
  const float* base = y1 + ((long long)b * 16) * N_ + n0;
#pragma unroll
  for (int c = 0; c < 16; ++c) {
    float2 v = *(const float2*)(base + (long long)c * N_);
    float h;
    h = fmaf(v.x, sc[c], sh[c]); h = h > 0.f ? h : 0.f; a0 = fmaf(w[c], h, a0);
    h = fmaf(v.y, sc[c], sh[c]); h = h > 0.f ? h : 0.f; a1 = fmaf(w[c], h, a1);
  }
  float2 o; o.x = a0; o.y = a1;
  *(float2*)(y2 + (long long)b * N_ + n0) = o;

  __syncthreads();   // hist zeroed before any atomic

  atomicAdd(&hist[key_map(a0) >> 20], 1);
  atomicAdd(&hist[key_map(a1) >> 20], 1);

  float ss = a0 + a1;
  float sq = fmaf(a0, a0, a1 * a1);
#pragma unroll
  for (int off = 32; off; off >>= 1) {
    ss += __shfl_down(ss, off, 64);
    sq += __shfl_down(sq, off, 64);
  }
  const int wid = t >> 6, lid = t & 63;
  if (lid == 0) { ls[wid] = ss; lq[wid] = sq; }
  __syncthreads();   // covers ls/lq stores AND hist atomics
  if (t == 0) {
    float Sv = 0.f, Qv = 0.f;
#pragma unroll
    for (int i = 0; i < 16; ++i) { Sv += ls[i]; Qv += lq[i]; }
    p2[blk * 2 + 0] = Sv;
    p2[blk * 2 + 1] = Qv;
  }
#pragma unroll
  for (int i = 0; i < NBINS / 1024; ++i) {
    int v = hist[t + i * 1024];
    if (v) atomicAdd(&ghist[b * NBINS + t + i * 1024], v);
  }
}

// --------------------------- k_thresh --------------------------------------
__global__ __launch_bounds__(256) void k_thresh(const int* __restrict__ ghist,
                                                int* __restrict__ Tb) {
  __shared__ int hl[NBINS + NBINS / 64];
  const int t = threadIdx.x, b = blockIdx.x;
  const int* h = ghist + b * NBINS;
  for (int i = t; i < NBINS; i += 256) hl[i + (i >> 6)] = h[i];
  __syncthreads();
  if (t < 64) {
    const int l = t;
    int s = 0;
    for (int j = 0; j < 64; ++j) s += hl[(l * 64 + j) + l];
    int Sv = s;
#pragma unroll
    for (int off = 1; off < 64; off <<= 1) {
      int v = __shfl_down(Sv, off, 64);
      if (l + off < 64) Sv += v;
    }
    unsigned long long m = __ballot(Sv >= K_);
    const int lstar = 63 - __builtin_clzll(m);
    const int tailS = (lstar < 63) ? __shfl(Sv, lstar + 1, 64) : 0;
    int Tj = hl[(lstar * 64 + l) + lstar];
#pragma unroll
    for (int off = 1; off < 64; off <<= 1) {
      int v = __shfl_down(Tj, off, 64);
      if (l + off < 64) Tj += v;
    }
    const int cge = Tj + tailS;
    unsigned long long m2 = __ballot(cge >= K_);
    const int jstar = 63 - __builtin_clzll(m2);
    if (l == 0) Tb[b] = lstar * 64 + jstar;
  }
}

// --------------------------- k_compact -------------------------------------
__global__ __launch_bounds__(1024) void k_compact(const float* __restrict__ y2,
                                                  const int* __restrict__ Tb,
                                                  int* __restrict__ cnt,
                                                  unsigned long long* __restrict__ cand) {
  const int t = threadIdx.x, blk = blockIdx.x;
  const int b  = blk >> 3;
  const int n0 = ((blk & 7) << 12) | (t << 2);
  const int T  = Tb[b];
  float4 v = *(const float4*)(y2 + (long long)b * N_ + n0);
  unsigned long long* cb = cand + (long long)b * CAP;
#define DO_CAND(comp, off)                                                    \
  {                                                                           \
    unsigned u = key_map(comp);                                               \
    if ((int)(u >> 20) >= T) {                                                \
      int slot = atomicAdd(&cnt[b], 1);                                       \
      if (slot < CAP)                                                         \
        cb[slot] = ((unsigned long long)u << 32) |                            \
                   (unsigned)(N_ - 1 - (n0 + off));                           \
    }                                                                         \
  }
  DO_CAND(v.x, 0) DO_CAND(v.y, 1) DO_CAND(v.z, 2) DO_CAND(v.w, 3)
#undef DO_CAND
}

// --------------------------- k_final ---------------------------------------
__global__ __launch_bounds__(64) void k_final(const unsigned long long* __restrict__ cand,
                                              const int* __restrict__ cnt,
                                              const float* __restrict__ p2,
                                              const float* __restrict__ g2,
                                              const float* __restrict__ bt2,
                                              const float* __restrict__ inp,
                                              float* __restrict__ out) {
  const int b = blockIdx.x, l = threadIdx.x;

  // stats2 from 256 block partials (fixed-order tree, same in all blocks)
  float s1 = (p2[2 * l] + p2[2 * (l + 64)]) +
             (p2[2 * (l + 128)] + p2[2 * (l + 192)]);
  float q1 = (p2[2 * l + 1] + p2[2 * (l + 64) + 1]) +
             (p2[2 * (l + 128) + 1] + p2[2 * (l + 192) + 1]);
#pragma unroll
  for (int off = 32; off; off >>= 1) {
    s1 += __shfl_down(s1, off, 64);
    q1 += __shfl_down(q1, off, 64);
  }
  s1 = __shfl(s1, 0, 64);
  q1 = __shfl(q1, 0, 64);
  const float inv = 1.f / (float)S_;
  const float mean = s1 * inv;
  const float var  = q1 * inv - mean * mean;
  const float scale2 = g2[0] * rsqrtf(var + EPS_);
  const float shift2 = bt2[0] - mean * scale2;

  int cn = cnt[b];
  if (cn > CAP) cn = CAP;
  const unsigned long long* cb = cand + (long long)b * CAP;
  unsigned long long k[16];
#pragma unroll
  for (int r = 0; r < 16; ++r) {
    int i = l + r * 64;
    k[r] = (i < cn) ? cb[i] : 0ull;
  }
  unsigned long long cur = 0ull;
#pragma unroll
  for (int r = 0; r < 16; ++r) cur = k[r] > cur ? k[r] : cur;

  int myidx = 0;
  unsigned mymap = 0;
  for (int r = 0; r < K_; ++r) {
    unsigned long long m = cur;
#pragma unroll
    for (int off = 32; off; off >>= 1) {
      unsigned long long o = __shfl_xor(m, off, 64);
      m = o > m ? o : m;
    }
    if (r == l) {
      myidx = N_ - 1 - (int)(m & 0xffffffffu);
      mymap = (unsigned)(m >> 32);
    }
    if (cur == m) {          // exactly one lane (keys unique)
#pragma unroll
      for (int r2 = 0; r2 < 16; ++r2)
        if (k[r2] == m) k[r2] = 0ull;
      unsigned long long c2 = 0ull;
#pragma unroll
      for (int r2 = 0; r2 < 16; ++r2) c2 = k[r2] > c2 ? k[r2] : c2;
      cur = c2;
    }
  }

  unsigned u = mymap;
  u = (u & 0x80000000u) ? (u & 0x7fffffffu) : ~u;
  float v = __uint_as_float(u);
  float scv = fmaf(v, scale2, shift2);
  scv = scv > 0.f ? scv : 0.f;

  const float* ib = inp + ((long long)b * 64) * N_;
#pragma unroll 4
  for (int f = 0; f < 64; ++f)
    out[((long long)b * 65 + f) * 64 + l] = ib[(long long)f * N_ + myidx];
  out[((long long)b * 65 + 64) * 64 + l] = scv;
  out[(long long)B_ * 65 * 64 + b * 64 + l] = (float)myidx;
}

// --------------------------- launch ----------------------------------------
extern "C" void kernel_launch(void* const* d_in, const int* in_sizes, int n_in,
                              void* d_out, int out_size, void* d_ws, size_t ws_size,
                              hipStream_t stream) {
  const float* sv  = (const float*)d_in[0];
  const float* inp = (const float*)d_in[1];
  const float* w0  = (const float*)d_in[2];
  const float* b0  = (const float*)d_in[3];
  const float* w1  = (const float*)d_in[4];
  const float* b1  = (const float*)d_in[5];
  const float* w2  = (const float*)d_in[6];
  const float* b2  = (const float*)d_in[7];
  const float* g0  = (const float*)d_in[8];
  const float* bt0 = (const float*)d_in[9];
  const float* g1  = (const float*)d_in[10];
  const float* bt1 = (const float*)d_in[11];
  const float* g2  = (const float*)d_in[12];
  const float* bt2 = (const float*)d_in[13];
  float* out = (float*)d_out;

  float* ws  = (float*)d_ws;
  float* y1  = ws;                                    // S*16     = 8388608
  float* y2  = y1 + (size_t)S_ * 16;                  // S        =  524288
  float* p0  = y2 + (size_t)S_;                       // 1024*128 =  131072
  float* p1  = p0 + (size_t)NS0B * 128;               // 1024*32  =   32768
  float* p2  = p1 + (size_t)NL1B * 32;                // 256*2    =     512
  float* st0 = p2 + (size_t)NB2 * 2;                  // 128
  float* st1 = st0 + 128;                             // 32
  float* w0T = st1 + 32;                              // 4096
  float* w1T = w0T + 4096;                            // 1024
  int*   ghist = (int*)(w1T + 1024);                  // 16*4096 ints
  int*   cnt   = ghist + (size_t)B_ * NBINS;          // 16 ints
  int*   Tb    = cnt + 16;                            // 16 ints
  unsigned long long* cand =
      (unsigned long long*)(Tb + 16);                 // 16*CAP u64

  hipMemsetAsync(ghist, 0, ((size_t)B_ * NBINS + 16) * sizeof(int), stream);

  k_prep   <<<1,     256, 0, stream>>>(w0, w1, w0T, w1T);
  k_stat0  <<<NS0B,  512, 0, stream>>>(sv, w0T, b0, p0);
  k_reduce0<<<1,    1024, 0, stream>>>(p0, g0, bt0, st0);
  k_layer01<<<NL1B,  512, 0, stream>>>(sv, w0T, b0, st0, w1T, b1, y1, p1);
  k_reduce1<<<1,    1024, 0, stream>>>(p1, g1, bt1, st1);
  k_layer2 <<<NB2,  1024, 0, stream>>>(y1, st1, w2, b2, y2, p2, ghist);
  k_thresh <<<B_,    256, 0, stream>>>(ghist, Tb);
  k_compact<<<NBC,  1024, 0, stream>>>(y2, Tb, cnt, cand);
  k_final  <<<B_,     64, 0, stream>>>(cand, cnt, p2, g2, bt2, inp, out);
}

// Round 8
// 291.104 us; speedup vs baseline: 1.4146x; 1.4146x over previous
//
#include <hip/hip_runtime.h>

// ---------------------------------------------------------------------------
// SortNet: 3-layer 1x1-conv MLP (64->64->16->1) with training-mode BatchNorm
// + ReLU, per-batch top-64 over N, gather of input + score.
//
// R8: R2's proven conv0 core (LDS tile, readfirstlane channel-group, s_load
// weights) + three targeted fixes:
//  - async double-buffered staging (global_load_lds w16, linear dest),
//    1 barrier/tile in k_stat0, 2 in k_layer01
//  - conv1 via register partials + zp LDS exchange (no h0 buffer, no conv1
//    ds_reads)
//  - fused select tail (stats2 + threshold + in-LDS compact + wave argmax +
//    gather in one 16-block kernel); ghist zeroed by k_stat0 (no memset)
// Launches: prep, stat0, reduce0, layer01, reduce1, layer2, select (7).
// ---------------------------------------------------------------------------

constexpr int   B_   = 16;
constexpr int   N_   = 32768;
constexpr int   K_   = 64;            // TOP_K
constexpr long long S_ = (long long)B_ * N_;   // 524288
constexpr float EPS_ = 1e-5f;

constexpr int NB0   = 2048;   // k_stat0 blocks, 4 tiles each (8192 tiles)
constexpr int NB1   = 2048;   // k_layer01 blocks, 4 tiles each
constexpr int NB2   = 256;    // k_layer2 blocks (2048 pos each)
constexpr int NBINS = 4096;   // radix-select bins (key >> 20)
constexpr int CAP   = 1024;   // candidate capacity per batch

__device__ __forceinline__ unsigned key_map(float f) {
  unsigned u = __float_as_uint(f);
  return (u & 0x80000000u) ? ~u : (u | 0x80000000u);
}

// async 16B global->LDS (dest is lane-linear by construction)
__device__ __forceinline__ void gload16(const float* g, float* l) {
  __builtin_amdgcn_global_load_lds(
      (const __attribute__((address_space(1))) void*)g,
      (__attribute__((address_space(3))) void*)l, 16, 0, 0);
}

// stage one 64-pos x 64-feat tile: thread issues 4 x 16B DMA, lane-contiguous
__device__ __forceinline__ void stage_tile(const float* __restrict__ src,
                                           float (*dst)[64], int t) {
#pragma unroll
  for (int q = 0; q < 4; ++q) {
    const int e = t + q * 256;
    const int f = e >> 4, c4 = (e & 15) << 2;
    gload16(src + (long long)f * N_ + c4, &dst[f][c4]);
  }
}

// --------------------------- k_prep ----------------------------------------
// w0T[f][o] = w0[o][f]; w1p[cg*256 + o*16 + j] = w1[o][cg*16 + j]
__global__ __launch_bounds__(256) void k_prep(const float* __restrict__ w0,
                                              const float* __restrict__ w1,
                                              float* __restrict__ w0T,
                                              float* __restrict__ w1p) {
  int t = threadIdx.x;
  for (int e = t; e < 64 * 64; e += 256) {
    int o = e >> 6, f = e & 63;
    w0T[f * 64 + o] = w0[e];
  }
  for (int e = t; e < 16 * 64; e += 256) {
    int cg = e >> 8, rem = e & 255, o = rem >> 4, j = rem & 15;
    w1p[e] = w1[o * 64 + cg * 16 + j];
  }
}

// --------------------------- k_stat0 ---------------------------------------
// R2 conv0 core + async dbuf staging, 1 barrier/tile. Also zeros ghist.
__global__ __launch_bounds__(256) void k_stat0(const float* __restrict__ sv,
                                               const float* __restrict__ w0T,
                                               const float* __restrict__ b0,
                                               float* __restrict__ p0,
                                               int* __restrict__ ghist) {
  __shared__ float svt[2][64][64];    // 2 x 16 KB
  const int t   = threadIdx.x;
  const int p   = t & 63;
  const int cg  = __builtin_amdgcn_readfirstlane(t >> 6);
  const int bid = blockIdx.x;

  if (t < 32) ghist[bid * 32 + t] = 0;   // 2048 blocks x 32 = 65536 ints

  float bb[16];
#pragma unroll
  for (int j = 0; j < 16; ++j) bb[j] = b0[cg * 16 + j];

  float s1[16], s2[16];
#pragma unroll
  for (int j = 0; j < 16; ++j) { s1[j] = 0.f; s2[j] = 0.f; }

  {
    const int tile = bid;
    const int b = tile >> 9, n0 = (tile & 511) << 6;
    stage_tile(sv + ((long long)b * 64) * N_ + n0, svt[0], t);
  }
  int cur = 0;
#pragma unroll
  for (int i = 0; i < 4; ++i) {
    __syncthreads();                     // drains DMA into svt[cur]
    if (i + 1 < 4) {
      const int tile = bid + (i + 1) * NB0;
      const int b = tile >> 9, n0 = (tile & 511) << 6;
      stage_tile(sv + ((long long)b * 64) * N_ + n0, svt[cur ^ 1], t);
    }
    float y[16];
#pragma unroll
    for (int j = 0; j < 16; ++j) y[j] = bb[j];
    for (int f = 0; f < 64; ++f) {
      const float x = svt[cur][f][p];
      const float* wr = w0T + f * 64 + cg * 16;   // wave-uniform -> s_load
#pragma unroll
      for (int j = 0; j < 16; ++j) y[j] = fmaf(wr[j], x, y[j]);
    }
#pragma unroll
    for (int j = 0; j < 16; ++j) {
      s1[j] += y[j];
      s2[j] = fmaf(y[j], y[j], s2[j]);
    }
    cur ^= 1;
  }

#pragma unroll
  for (int j = 0; j < 16; ++j) {
#pragma unroll
    for (int off = 32; off; off >>= 1) {
      s1[j] += __shfl_down(s1[j], off, 64);
      s2[j] += __shfl_down(s2[j], off, 64);
    }
  }
  if (p == 0) {
    float* dst = p0 + (long long)bid * 128;
#pragma unroll
    for (int j = 0; j < 16; ++j) {
      dst[cg * 16 + j]      = s1[j];
      dst[64 + cg * 16 + j] = s2[j];
    }
  }
}

// --------------------------- k_reduce0 -------------------------------------
__global__ __launch_bounds__(1024) void k_reduce0(const float* __restrict__ p0,
                                                  const float* __restrict__ g,
                                                  const float* __restrict__ bt,
                                                  float* __restrict__ st) {
  __shared__ float l[8][128];
  const int t = threadIdx.x;
  const int j = t & 127, grp = t >> 7;
  float a = 0.f;
  for (int i = grp; i < NB0; i += 8) a += p0[(long long)i * 128 + j];
  l[grp][j] = a;
  __syncthreads();
  if (t < 128) {
    float v = ((l[0][t] + l[1][t]) + (l[2][t] + l[3][t])) +
              ((l[4][t] + l[5][t]) + (l[6][t] + l[7][t]));
    l[0][t] = v;
  }
  __syncthreads();
  if (t < 64) {
    const float inv = 1.f / (float)S_;
    float mean = l[0][t] * inv;
    float ex2  = l[0][64 + t] * inv;
    float var  = ex2 - mean * mean;
    float sc   = g[t] * rsqrtf(var + EPS_);
    st[t]      = sc;
    st[64 + t] = bt[t] - mean * sc;
  }
}

// --------------------------- k_layer01 -------------------------------------
// conv0 (R2 core, dbuf staging) -> bn+relu in registers -> conv1 register
// partials -> zp LDS exchange -> z, y1, stats1. 2 barriers/tile.
__global__ __launch_bounds__(256) void k_layer01(const float* __restrict__ sv,
                                                 const float* __restrict__ w0T,
                                                 const float* __restrict__ b0,
                                                 const float* __restrict__ st0,
                                                 const float* __restrict__ w1p,
                                                 const float* __restrict__ b1,
                                                 float* __restrict__ y1,
                                                 float* __restrict__ p1) {
  __shared__ float svt[2][64][64];    // 32 KB
  __shared__ float zp[4][16][64];     // 16 KB
  const int t   = threadIdx.x;
  const int p   = t & 63;
  const int cg  = __builtin_amdgcn_readfirstlane(t >> 6);
  const int bid = blockIdx.x;

  float bb[16], sc[16], sh[16];
#pragma unroll
  for (int j = 0; j < 16; ++j) {
    bb[j] = b0[cg * 16 + j];
    sc[j] = st0[cg * 16 + j];
    sh[j] = st0[64 + cg * 16 + j];
  }
  float bb1[4];
#pragma unroll
  for (int j = 0; j < 4; ++j) bb1[j] = b1[cg * 4 + j];

  float sA[4], qA[4];
#pragma unroll
  for (int j = 0; j < 4; ++j) { sA[j] = 0.f; qA[j] = 0.f; }

  {
    const int tile = bid;
    const int b = tile >> 9, n0 = (tile & 511) << 6;
    stage_tile(sv + ((long long)b * 64) * N_ + n0, svt[0], t);
  }
  int cur = 0;
#pragma unroll
  for (int i = 0; i < 4; ++i) {
    const int tile = bid + i * NB0;
    const int b = tile >> 9, n0 = (tile & 511) << 6;

    __syncthreads();                   // bar A: svt[cur] ready, zp reads done
    if (i + 1 < 4) {
      const int tile2 = bid + (i + 1) * NB0;
      const int b2 = tile2 >> 9, n02 = (tile2 & 511) << 6;
      stage_tile(sv + ((long long)b2 * 64) * N_ + n02, svt[cur ^ 1], t);
    }

    // conv0
    float y[16];
#pragma unroll
    for (int j = 0; j < 16; ++j) y[j] = bb[j];
    for (int f = 0; f < 64; ++f) {
      const float x = svt[cur][f][p];
      const float* wr = w0T + f * 64 + cg * 16;
#pragma unroll
      for (int j = 0; j < 16; ++j) y[j] = fmaf(wr[j], x, y[j]);
    }
    // bn0 + relu in registers
#pragma unroll
    for (int j = 0; j < 16; ++j) {
      float h = fmaf(y[j], sc[j], sh[j]);
      y[j] = h > 0.f ? h : 0.f;
    }
    // conv1 register partials: zp[cg][o][p] = sum_j w1[o][cg*16+j]*h[j]
    const float* wp = w1p + cg * 256;            // wave-uniform -> s_load
#pragma unroll
    for (int o = 0; o < 16; ++o) {
      float acc = 0.f;
#pragma unroll
      for (int j = 0; j < 16; ++j) acc = fmaf(wp[o * 16 + j], y[j], acc);
      zp[cg][o][p] = acc;
    }
    __syncthreads();                   // bar B: zp complete

    // cross-wave reduce: thread (p, cg) -> out-ch cg*4+oi
    float* yo = y1 + ((long long)(b * 16 + cg * 4)) * N_ + n0 + p;
#pragma unroll
    for (int oi = 0; oi < 4; ++oi) {
      const int o = cg * 4 + oi;
      float z = ((zp[0][o][p] + zp[1][o][p]) +
                 (zp[2][o][p] + zp[3][o][p])) + bb1[oi];
      yo[(long long)oi * N_] = z;
      sA[oi] += z;
      qA[oi] = fmaf(z, z, qA[oi]);
    }
    cur ^= 1;
  }

#pragma unroll
  for (int j = 0; j < 4; ++j) {
#pragma unroll
    for (int off = 32; off; off >>= 1) {
      sA[j] += __shfl_down(sA[j], off, 64);
      qA[j] += __shfl_down(qA[j], off, 64);
    }
  }
  if (p == 0) {
    float* dst = p1 + (long long)bid * 32;
#pragma unroll
    for (int j = 0; j < 4; ++j) {
      dst[cg * 4 + j]      = sA[j];
      dst[16 + cg * 4 + j] = qA[j];
    }
  }
}

// --------------------------- k_reduce1 -------------------------------------
__global__ __launch_bounds__(1024) void k_reduce1(const float* __restrict__ p1,
                                                  const float* __restrict__ g,
                                                  const float* __restrict__ bt,
                                                  float* __restrict__ st) {
  __shared__ float l[32][32];
  const int t = threadIdx.x;
  const int j = t & 31, grp = t >> 5;
  float a = 0.f;
  for (int i = grp; i < NB1; i += 32) a += p1[(long long)i * 32 + j];
  l[grp][j] = a;
  __syncthreads();
  if (t < 32) {
    float v = 0.f;
#pragma unroll
    for (int g2 = 0; g2 < 32; ++g2) v += l[g2][t];
    l[0][t] = v;
  }
  __syncthreads();
  if (t < 16) {
    const float inv = 1.f / (float)S_;
    float mean = l[0][t] * inv;
    float ex2  = l[0][16 + t] * inv;
    float var  = ex2 - mean * mean;
    float sc   = g[t] * rsqrtf(var + EPS_);
    st[t]      = sc;
    st[16 + t] = bt[t] - mean * sc;
  }
}

// --------------------------- k_layer2 --------------------------------------
__global__ __launch_bounds__(1024) void k_layer2(const float* __restrict__ y1,
                                                 const float* __restrict__ st1,
                                                 const float* __restrict__ w2,
                                                 const float* __restrict__ b2,
                                                 float* __restrict__ y2,
                                                 float* __restrict__ p2,
                                                 int* __restrict__ ghist) {
  __shared__ int hist[NBINS];
  __shared__ float ls[16], lq[16];
  const int t   = threadIdx.x;
  const int blk = blockIdx.x;
  const int b   = blk >> 4;
  const int n0  = ((blk & 15) << 11) | (t << 1);

#pragma unroll
  for (int i = 0; i < NBINS / 1024; ++i) hist[t + i * 1024] = 0;

  float sc[16], sh[16], w[16];
#pragma unroll
  for (int c = 0; c < 16; ++c) { sc[c] = st1[c]; sh[c] = st1[16 + c]; w[c] = w2[c]; }
  const float bias = b2[0];

  float a0 = bias, a1 = bias;
  const float* base = y1 + ((long long)b * 16) * N_ + n0;
#pragma unroll
  for (int c = 0; c < 16; ++c) {
    float2 v = *(const float2*)(base + (long long)c * N_);
    float h;
    h = fmaf(v.x, sc[c], sh[c]); h = h > 0.f ? h : 0.f; a0 = fmaf(w[c], h, a0);
    h = fmaf(v.y, sc[c], sh[c]); h = h > 0.f ? h : 0.f; a1 = fmaf(w[c], h, a1);
  }
  float2 o; o.x = a0; o.y = a1;
  *(float2*)(y2 + (long long)b * N_ + n0) = o;

  __syncthreads();

  atomicAdd(&hist[key_map(a0) >> 20], 1);
  atomicAdd(&hist[key_map(a1) >> 20], 1);

  float ss = a0 + a1;
  float sq = fmaf(a0, a0, a1 * a1);
#pragma unroll
  for (int off = 32; off; off >>= 1) {
    ss += __shfl_down(ss, off, 64);
    sq += __shfl_down(sq, off, 64);
  }
  const int wid = t >> 6, lid = t & 63;
  if (lid == 0) { ls[wid] = ss; lq[wid] = sq; }
  __syncthreads();
  if (t == 0) {
    float Sv = 0.f, Qv = 0.f;
#pragma unroll
    for (int i = 0; i < 16; ++i) { Sv += ls[i]; Qv += lq[i]; }
    p2[blk * 2 + 0] = Sv;
    p2[blk * 2 + 1] = Qv;
  }
#pragma unroll
  for (int i = 0; i < NBINS / 1024; ++i) {
    int v = hist[t + i * 1024];
    if (v) atomicAdd(&ghist[b * NBINS + t + i * 1024], v);
  }
}

// --------------------------- k_select --------------------------------------
// One block per batch: stats2 finalize, threshold scan, in-LDS compact,
// wave-0 argmax (jax tie-break), gather. Deterministic output.
__global__ __launch_bounds__(1024) void k_select(const float* __restrict__ y2,
                                                 const int* __restrict__ ghist,
                                                 const float* __restrict__ p2,
                                                 const float* __restrict__ g2,
                                                 const float* __restrict__ bt2,
                                                 const float* __restrict__ inp,
                                                 float* __restrict__ out) {
  __shared__ int hl[NBINS + NBINS / 64];
  __shared__ float sred[512];
  __shared__ unsigned long long cand[CAP];
  __shared__ int lcnt;
  __shared__ int sT;
  __shared__ float s2v[2];
  __shared__ int   idxs[K_];
  __shared__ float scores[K_];

  const int t = threadIdx.x, b = blockIdx.x;
  const int* h = ghist + b * NBINS;
  for (int i = t; i < NBINS; i += 1024) hl[i + (i >> 6)] = h[i];
  if (t < 512) sred[t] = p2[t];
  if (t == 0) lcnt = 0;
  __syncthreads();
  // p2 tree-reduce keeping parity: sred[0]=sum, sred[1]=sumsq
  for (int s = 256; s >= 2; s >>= 1) {
    if (t < s) sred[t] += sred[t + s];
    __syncthreads();
  }
  if (t == 0) {
    const float inv = 1.f / (float)S_;
    float mean = sred[0] * inv;
    float var  = sred[1] * inv - mean * mean;
    float scv  = g2[0] * rsqrtf(var + EPS_);
    s2v[0] = scv;
    s2v[1] = bt2[0] - mean * scv;
  }
  if (t < 64) {
    const int l = t;
    int s = 0;
    for (int j = 0; j < 64; ++j) s += hl[(l * 64 + j) + l];
    int Sv = s;
#pragma unroll
    for (int off = 1; off < 64; off <<= 1) {
      int v = __shfl_down(Sv, off, 64);
      if (l + off < 64) Sv += v;
    }
    unsigned long long m = __ballot(Sv >= K_);
    const int lstar = 63 - __builtin_clzll(m);
    const int tailS = (lstar < 63) ? __shfl(Sv, lstar + 1, 64) : 0;
    int Tj = hl[(lstar * 64 + l) + lstar];
#pragma unroll
    for (int off = 1; off < 64; off <<= 1) {
      int v = __shfl_down(Tj, off, 64);
      if (l + off < 64) Tj += v;
    }
    const int cge = Tj + tailS;
    unsigned long long m2 = __ballot(cge >= K_);
    const int jstar = 63 - __builtin_clzll(m2);
    if (l == 0) sT = lstar * 64 + jstar;
  }
  __syncthreads();

  const int T = sT;
  const float* yrow = y2 + (long long)b * N_;
  for (int it = 0; it < 8; ++it) {
    const int n0 = (it << 12) | (t << 2);
    float4 v = *(const float4*)(yrow + n0);
#define DO_CAND(comp, off)                                                    \
    {                                                                         \
      unsigned u = key_map(comp);                                             \
      if ((int)(u >> 20) >= T) {                                              \
        int slot = atomicAdd(&lcnt, 1);                                       \
        if (slot < CAP)                                                       \
          cand[slot] = ((unsigned long long)u << 32) |                        \
                       (unsigned)(N_ - 1 - (n0 + off));                       \
      }                                                                       \
    }
    DO_CAND(v.x, 0) DO_CAND(v.y, 1) DO_CAND(v.z, 2) DO_CAND(v.w, 3)
#undef DO_CAND
  }
  __syncthreads();

  if (t < 64) {
    const int l = t;
    int cn = lcnt;
    if (cn > CAP) cn = CAP;
    unsigned long long k[16];
#pragma unroll
    for (int r = 0; r < 16; ++r) {
      int i = l + r * 64;
      k[r] = (i < cn) ? cand[i] : 0ull;
    }
    unsigned long long curk = 0ull;
#pragma unroll
    for (int r = 0; r < 16; ++r) curk = k[r] > curk ? k[r] : curk;

    int myidx = 0;
    unsigned mymap = 0;
    for (int r = 0; r < K_; ++r) {
      unsigned long long m = curk;
#pragma unroll
      for (int off = 32; off; off >>= 1) {
        unsigned long long o = __shfl_xor(m, off, 64);
        m = o > m ? o : m;
      }
      if (r == l) {
        myidx = N_ - 1 - (int)(m & 0xffffffffu);
        mymap = (unsigned)(m >> 32);
      }
      if (curk == m) {        // exactly one lane (keys unique by index part)
#pragma unroll
        for (int r2 = 0; r2 < 16; ++r2)
          if (k[r2] == m) k[r2] = 0ull;
        unsigned long long c2 = 0ull;
#pragma unroll
        for (int r2 = 0; r2 < 16; ++r2) c2 = k[r2] > c2 ? k[r2] : c2;
        curk = c2;
      }
    }
    unsigned u = mymap;
    u = (u & 0x80000000u) ? (u & 0x7fffffffu) : ~u;
    float v = __uint_as_float(u);
    float scv = fmaf(v, s2v[0], s2v[1]);
    scores[l] = scv > 0.f ? scv : 0.f;
    idxs[l]   = myidx;
  }
  __syncthreads();

  const float* ib = inp + ((long long)b * 64) * N_;
  for (int e = t; e < 65 * 64; e += 1024) {
    const int f = e >> 6, k = e & 63;
    out[((long long)b * 65 + f) * 64 + k] =
        (f < 64) ? ib[(long long)f * N_ + idxs[k]] : scores[k];
  }
  if (t < K_) out[(long long)B_ * 65 * 64 + b * 64 + t] = (float)idxs[t];
}

// --------------------------- launch ----------------------------------------
extern "C" void kernel_launch(void* const* d_in, const int* in_sizes, int n_in,
                              void* d_out, int out_size, void* d_ws, size_t ws_size,
                              hipStream_t stream) {
  const float* sv  = (const float*)d_in[0];
  const float* inp = (const float*)d_in[1];
  const float* w0  = (const float*)d_in[2];
  const float* b0  = (const float*)d_in[3];
  const float* w1  = (const float*)d_in[4];
  const float* b1  = (const float*)d_in[5];
  const float* w2  = (const float*)d_in[6];
  const float* b2  = (const float*)d_in[7];
  const float* g0  = (const float*)d_in[8];
  const float* bt0 = (const float*)d_in[9];
  const float* g1  = (const float*)d_in[10];
  const float* bt1 = (const float*)d_in[11];
  const float* g2  = (const float*)d_in[12];
  const float* bt2 = (const float*)d_in[13];
  float* out = (float*)d_out;

  float* ws  = (float*)d_ws;
  float* y1  = ws;                                    // S*16     = 8388608
  float* y2  = y1 + (size_t)S_ * 16;                  // S        =  524288
  float* p0  = y2 + (size_t)S_;                       // 2048*128 =  262144
  float* p1  = p0 + (size_t)NB0 * 128;                // 2048*32  =   65536
  float* p2  = p1 + (size_t)NB1 * 32;                 // 512
  float* st0 = p2 + 512;                              // 128
  float* st1 = st0 + 128;                             // 32
  float* w0T = st1 + 32;                              // 4096
  float* w1p = w0T + 4096;                            // 1024
  int*   ghist = (int*)(w1p + 1024);                  // 16*4096 ints

  k_prep   <<<1,     256, 0, stream>>>(w0, w1, w0T, w1p);
  k_stat0  <<<NB0,   256, 0, stream>>>(sv, w0T, b0, p0, ghist);
  k_reduce0<<<1,    1024, 0, stream>>>(p0, g0, bt0, st0);
  k_layer01<<<NB1,   256, 0, stream>>>(sv, w0T, b0, st0, w1p, b1, y1, p1);
  k_reduce1<<<1,    1024, 0, stream>>>(p1, g1, bt1, st1);
  k_layer2 <<<NB2,  1024, 0, stream>>>(y1, st1, w2, b2, y2, p2, ghist);
  k_select <<<B_,   1024, 0, stream>>>(y2, ghist, p2, g2, bt2, inp, out);
}